// Round 8
// baseline (1070.009 us; speedup 1.0000x reference)
//
#include <hip/hip_runtime.h>
#include <hip/hip_bf16.h>

#define D 128
#define CAP 64      // max edges per src node (Poisson(16); verified on real data)
#define GCAP 192    // max nodes per graph  (Poisson(97.7); verified on real data)
#define LSTRIDE 132 // LDS row stride in shorts (2-way conflict max = free)
#define CPAD 16     // one 64B line per counter
#define NBLK 1024   // 4 blocks/CU x 256 CUs; residency forced by __launch_bounds__(256,4)

typedef __attribute__((ext_vector_type(8))) short short8;
typedef __attribute__((ext_vector_type(4))) float f32x4;

__device__ __forceinline__ float b2f(unsigned short u) {
    union { unsigned int i; float f; } v;
    v.i = ((unsigned int)u) << 16;
    return v.f;
}
__device__ __forceinline__ unsigned short f2b(float f) {
    __hip_bfloat16 h = __float2bfloat16(f);   // RNE
    return __builtin_bit_cast(unsigned short, h);
}

struct KParams {
    const float* X;
    const int* esrc; const int* edst; const float* eval;
    const int* bids; const float* bval;
    const float* W1; const float* b1; const float* W2;
    const float* Wg; const float* bg;
    unsigned short* W1hi; unsigned short* W1lo;
    unsigned short* W2hi; unsigned short* W2lo;
    int* bar;                       // grid barrier counter (memset 0 pre-launch)
    int* cnt; int* gcnt;            // padded counters, gcnt contiguous after cnt
    unsigned short* hw;
    int2* edata; int2* gdata;
    float* hstruct; float* hgraph;
    int N, E, G, gemmTiles, nEdgeChunks, nNodeChunks;
};

// Hand-rolled grid barrier: monotone arrival counter, device-scope.
// Safe because all NBLK blocks are co-resident (forced occupancy) and every
// block calls it the same number of times with no early returns.
__device__ __forceinline__ void grid_barrier(int* bar, int target) {
    __syncthreads();
    if (threadIdx.x == 0) {
        __threadfence();                         // release my writes device-wide
        atomicAdd(bar, 1);
        while (atomicAdd(bar, 0) < target)       // atomic load, device scope
            __builtin_amdgcn_s_sleep(2);
        __threadfence();                         // acquire others' writes
    }
    __syncthreads();
}

// Fused double GEMM for one 64-row tile: hw = relu(x@W1+b1) @ W2, bf16 out.
// GEMM1 fp32-accurate via hi/lo bf16 split (3 MFMAs/tile); h parked bf16 in
// wave-private LDS (C-layout -> A-layout), GEMM2 = 2 MFMAs vs split W2.
__device__ __forceinline__ void gemm_tile(
        const float* __restrict__ X,
        const unsigned short* __restrict__ W1hi, const unsigned short* __restrict__ W1lo,
        const float* __restrict__ b1,
        const unsigned short* __restrict__ W2hi, const unsigned short* __restrict__ W2lo,
        unsigned short* __restrict__ HW, int N, int t, unsigned short* tile) {
    const int lane = threadIdx.x & 63;
    const int q = lane >> 4;
    const int l15 = lane & 15;
    const int wave = threadIdx.x >> 6;
    const int row0 = t * 64 + wave * 16;

    int arow = row0 + l15;
    if (arow >= N) arow = N - 1;                  // clamp; stores guarded
    const float* xrow = X + (size_t)arow * D;

    f32x4 acc[8];
#pragma unroll
    for (int i = 0; i < 8; i++) acc[i] = (f32x4){0.f, 0.f, 0.f, 0.f};

#pragma unroll
    for (int kk = 0; kk < 4; kk++) {
        float4 f0 = *(const float4*)(xrow + kk * 32 + q * 8);
        float4 f1 = *(const float4*)(xrow + kk * 32 + q * 8 + 4);
        float fv[8] = {f0.x, f0.y, f0.z, f0.w, f1.x, f1.y, f1.z, f1.w};
        short8 ahi, alo;
#pragma unroll
        for (int j = 0; j < 8; j++) {
            unsigned short h = f2b(fv[j]);
            ahi[j] = (short)h;
            alo[j] = (short)f2b(fv[j] - b2f(h));
        }
#pragma unroll
        for (int i = 0; i < 8; i++) {
            size_t woff = (size_t)(i * 16 + l15) * D + kk * 32 + q * 8;
            short8 bhi = *(const short8*)(W1hi + woff);
            short8 blo = *(const short8*)(W1lo + woff);
            acc[i] = __builtin_amdgcn_mfma_f32_16x16x32_bf16(ahi, bhi, acc[i], 0, 0, 0);
            acc[i] = __builtin_amdgcn_mfma_f32_16x16x32_bf16(ahi, blo, acc[i], 0, 0, 0);
            acc[i] = __builtin_amdgcn_mfma_f32_16x16x32_bf16(alo, bhi, acc[i], 0, 0, 0);
        }
    }

#pragma unroll
    for (int i = 0; i < 8; i++) {
        int col = i * 16 + l15;
        float bv = b1[col];
#pragma unroll
        for (int r = 0; r < 4; r++) {
            float v = acc[i][r] + bv;
            v = v > 0.f ? v : 0.f;
            tile[(q * 4 + r) * LSTRIDE + col] = f2b(v);
        }
    }

#pragma unroll
    for (int i = 0; i < 8; i++) acc[i] = (f32x4){0.f, 0.f, 0.f, 0.f};
#pragma unroll
    for (int kk = 0; kk < 4; kk++) {
        short8 ahi = *(const short8*)(tile + l15 * LSTRIDE + kk * 32 + q * 8);
#pragma unroll
        for (int i = 0; i < 8; i++) {
            size_t woff = (size_t)(i * 16 + l15) * D + kk * 32 + q * 8;
            short8 bhi = *(const short8*)(W2hi + woff);
            short8 blo = *(const short8*)(W2lo + woff);
            acc[i] = __builtin_amdgcn_mfma_f32_16x16x32_bf16(ahi, bhi, acc[i], 0, 0, 0);
            acc[i] = __builtin_amdgcn_mfma_f32_16x16x32_bf16(ahi, blo, acc[i], 0, 0, 0);
        }
    }

#pragma unroll
    for (int i = 0; i < 8; i++) {
        int col = i * 16 + l15;
#pragma unroll
        for (int r = 0; r < 4; r++) {
            int row = row0 + q * 4 + r;
            if (row < N) HW[(size_t)row * D + col] = f2b(acc[i][r]);
        }
    }
}

// ---------------------------------------------------------------------------
// One persistent kernel, 4 phases, hand-rolled grid barriers. Normal launch
// (graph-capture safe). Phase 1 interleaves GEMM (even blocks) and CSR build
// (odd blocks) — guaranteed co-resident.
__global__ __launch_bounds__(256, 4) void k_all(KParams p) {
    __shared__ unsigned short lds[4 * 16 * LSTRIDE];   // 16.9 KB
    const int tid = blockIdx.x * 256 + threadIdx.x;
    const int nthr = gridDim.x * 256;

    // ---- Phase 0: weight transpose+split, zero padded counters ----
    for (int i = tid; i < 2 * D * D; i += nthr) {
        int j = i & (D * D - 1);
        const float* W = (i < D * D) ? p.W1 : p.W2;
        unsigned short* Hi = (i < D * D) ? p.W1hi : p.W2hi;
        unsigned short* Lo = (i < D * D) ? p.W1lo : p.W2lo;
        int k = j >> 7, n = j & 127;
        float w = W[j];
        unsigned short hi = f2b(w);
        unsigned short lo = f2b(w - b2f(hi));
        Hi[n * D + k] = hi;
        Lo[n * D + k] = lo;
    }
    for (int i = tid; i < p.N + p.G; i += nthr) p.cnt[i * CPAD] = 0;  // covers gcnt too
    grid_barrier(p.bar, gridDim.x);

    // ---- Phase 1: even blocks GEMM, odd blocks CSR build ----
    const int half = gridDim.x >> 1;
    const int myIdx = blockIdx.x >> 1;
    if (blockIdx.x & 1) {
        for (int c = myIdx; c < p.nEdgeChunks; c += half) {
            int base = c * 1024 + threadIdx.x;
#pragma unroll
            for (int u = 0; u < 4; u++) {              // 4 independent chains
                int e = base + u * 256;
                if (e < p.E) {
                    int s = p.esrc[e];
                    int slot = atomicAdd(&p.cnt[s * CPAD], 1);
                    if (slot < CAP) {
                        int2 d; d.x = p.edst[e]; d.y = __float_as_int(p.eval[e]);
                        p.edata[(size_t)s * CAP + slot] = d;
                    }
                }
            }
        }
        for (int c = myIdx; c < p.nNodeChunks; c += half) {
            int base = c * 1024 + threadIdx.x;
#pragma unroll
            for (int u = 0; u < 4; u++) {
                int i = base + u * 256;
                if (i < p.N) {
                    int g = p.bids[i];
                    int slot = atomicAdd(&p.gcnt[g * CPAD], 1);
                    if (slot < GCAP) {
                        int2 d; d.x = i; d.y = __float_as_int(p.bval[i]);
                        p.gdata[(size_t)g * GCAP + slot] = d;
                    }
                }
            }
        }
    } else {
        unsigned short* tile = lds + (threadIdx.x >> 6) * 16 * LSTRIDE;
        for (int t = myIdx; t < p.gemmTiles; t += half)
            gemm_tile(p.X, p.W1hi, p.W1lo, p.b1, p.W2hi, p.W2lo, p.hw, p.N, t, tile);
    }
    grid_barrier(p.bar, 2 * gridDim.x);

    // ---- Phase 2: one wave per node — gather, relu, l2norm, write h_struct ----
    const int lane = threadIdx.x & 63;
    const int waveId = tid >> 6;
    const int nwaves = nthr >> 6;
    const unsigned int* hw32 = (const unsigned int*)p.hw;
    for (int node = waveId; node < p.N; node += nwaves) {
        int deg = p.cnt[node * CPAD];
        if (deg > CAP) deg = CAP;
        int myDst = 0; float myVal = 0.f;
        if (lane < deg) {
            int2 ed = p.edata[(size_t)node * CAP + lane];
            myDst = ed.x; myVal = __int_as_float(ed.y);
        }
        float a0 = 0.f, a1 = 0.f;
#pragma unroll 4
        for (int j = 0; j < deg; j++) {
            int dj = __shfl(myDst, j, 64);
            float vj = __shfl(myVal, j, 64);
            unsigned int pk = hw32[(size_t)dj * 64 + lane];
            a0 = fmaf(vj, b2f((unsigned short)(pk & 0xffffu)), a0);
            a1 = fmaf(vj, b2f((unsigned short)(pk >> 16)), a1);
        }
        a0 = a0 > 0.f ? a0 : 0.f;
        a1 = a1 > 0.f ? a1 : 0.f;
        float ss = a0 * a0 + a1 * a1;
#pragma unroll
        for (int m = 1; m < 64; m <<= 1) ss += __shfl_xor(ss, m, 64);
        float scale = 1.0f / fmaxf(sqrtf(ss), 1e-12f);
        float2 o; o.x = a0 * scale; o.y = a1 * scale;
        *(float2*)(p.hstruct + (size_t)node * D + 2 * lane) = o;
    }
    grid_barrier(p.bar, 3 * gridDim.x);

    // ---- Phase 3: one wave per graph — pool, GEMM via shfl, l2norm ----
    const int c0 = 2 * lane;
    for (int g = waveId; g < p.G; g += nwaves) {
        int deg = p.gcnt[g * CPAD];
        if (deg > GCAP) deg = GCAP;
        float a0 = 0.f, a1 = 0.f;
        for (int base = 0; base < deg; base += 64) {
            int nrem = deg - base; if (nrem > 64) nrem = 64;
            int myNode = 0; float myW = 0.f;
            if (lane < nrem) {
                int2 ed = p.gdata[(size_t)g * GCAP + base + lane];
                myNode = ed.x; myW = __int_as_float(ed.y);
            }
#pragma unroll 4
            for (int j = 0; j < nrem; j++) {
                int nj = __shfl(myNode, j, 64);
                float wj = __shfl(myW, j, 64);
                float2 hs = *(const float2*)(p.hstruct + (size_t)nj * D + c0);
                a0 = fmaf(wj, hs.x, a0);
                a1 = fmaf(wj, hs.y, a1);
            }
        }
        float o0 = 0.f, o1 = 0.f;
#pragma unroll 2
        for (int k = 0; k < D; k++) {
            float xv = (k & 1) ? __shfl(a1, k >> 1, 64) : __shfl(a0, k >> 1, 64);
            float2 w = *(const float2*)(p.Wg + (size_t)k * D + c0);
            o0 = fmaf(xv, w.x, o0);
            o1 = fmaf(xv, w.y, o1);
        }
        o0 += p.bg[c0];
        o1 += p.bg[c0 + 1];
        o0 = o0 > 0.f ? o0 : 0.f;
        o1 = o1 > 0.f ? o1 : 0.f;
        float ss = o0 * o0 + o1 * o1;
#pragma unroll
        for (int m = 1; m < 64; m <<= 1) ss += __shfl_xor(ss, m, 64);
        float scale = 1.0f / fmaxf(sqrtf(ss), 1e-12f);
        float2 o; o.x = o0 * scale; o.y = o1 * scale;
        *(float2*)(p.hgraph + (size_t)g * D + c0) = o;
    }
}

// ---------------------------------------------------------------------------
extern "C" void kernel_launch(void* const* d_in, const int* in_sizes, int n_in,
                              void* d_out, int out_size, void* d_ws, size_t ws_size,
                              hipStream_t stream) {
    KParams p;
    p.X    = (const float*)d_in[0];
    p.esrc = (const int*)d_in[1];
    p.edst = (const int*)d_in[2];
    p.eval = (const float*)d_in[3];
    p.bids = (const int*)d_in[4];
    p.bval = (const float*)d_in[5];
    p.W1   = (const float*)d_in[6];
    p.b1   = (const float*)d_in[7];
    p.W2   = (const float*)d_in[8];
    p.Wg   = (const float*)d_in[9];
    p.bg   = (const float*)d_in[10];

    p.N = in_sizes[4];
    p.E = in_sizes[1];
    p.G = 1024;

    char* ws = (char*)d_ws;
    p.bar  = (int*)ws;            ws += 64;
    p.W1hi = (unsigned short*)ws; ws += (size_t)D * D * 2;
    p.W1lo = (unsigned short*)ws; ws += (size_t)D * D * 2;
    p.W2hi = (unsigned short*)ws; ws += (size_t)D * D * 2;
    p.W2lo = (unsigned short*)ws; ws += (size_t)D * D * 2;
    p.cnt  = (int*)ws;            ws += (size_t)p.N * CPAD * 4;
    p.gcnt = (int*)ws;            ws += (size_t)p.G * CPAD * 4;  // contiguous after cnt
    p.hw   = (unsigned short*)ws; ws += (size_t)p.N * D * 2;
    p.edata = (int2*)ws;          ws += (size_t)p.N * CAP * 8;
    p.gdata = (int2*)ws;          ws += (size_t)p.G * GCAP * 8;

    p.hstruct = (float*)d_out;
    p.hgraph  = p.hstruct + (size_t)p.N * D;

    p.gemmTiles   = (p.N + 63) / 64;
    p.nEdgeChunks = (p.E + 1023) / 1024;
    p.nNodeChunks = (p.N + 1023) / 1024;

    hipMemsetAsync(p.bar, 0, 64, stream);   // barrier counter must start at 0
    k_all<<<NBLK, 256, 0, stream>>>(p);
}

// Round 9
// 503.126 us; speedup vs baseline: 2.1267x; 2.1267x over previous
//
#include <hip/hip_runtime.h>
#include <hip/hip_bf16.h>

#define D 128
#define CAP 64      // max edges per src node (Poisson(16); verified on real data)
#define GCAP 192    // max nodes per graph  (Poisson(97.7); verified on real data)
#define LSTRIDE 132 // LDS row stride in shorts (2-way conflict max = free)
#define CPN 4       // cnt padding: 4 counters/64B line, 1.6MB (L2-resident)
#define CPG 16      // gcnt padding: 1 counter/64B line, 64KB

typedef __attribute__((ext_vector_type(8))) short short8;
typedef __attribute__((ext_vector_type(4))) float f32x4;

__device__ __forceinline__ float b2f(unsigned short u) {
    union { unsigned int i; float f; } v;
    v.i = ((unsigned int)u) << 16;
    return v.f;
}
__device__ __forceinline__ unsigned short f2b(float f) {
    __hip_bfloat16 h = __float2bfloat16(f);   // RNE
    return __builtin_bit_cast(unsigned short, h);
}

// ---------------------------------------------------------------------------
// blocks 0..127: weight transpose + hi/lo bf16 split (W_in, W_gcn).
// blocks 128.. : zero the padded counters (only the slots we read).
__global__ void k_prep(const float* __restrict__ Wa, unsigned short* __restrict__ Ahi,
                       unsigned short* __restrict__ Alo,
                       const float* __restrict__ Wb, unsigned short* __restrict__ Bhi,
                       unsigned short* __restrict__ Blo,
                       int* __restrict__ cnt, int N,
                       int* __restrict__ gcnt, int G) {
    int b = blockIdx.x;
    if (b >= 128) {
        int idx = (b - 128) * 256 + threadIdx.x;
        if (idx < N) cnt[idx * CPN] = 0;
        if (idx < G) gcnt[idx * CPG] = 0;
        return;
    }
    const float* W = (b < 64) ? Wa : Wb;
    unsigned short* Hi = (b < 64) ? Ahi : Bhi;
    unsigned short* Lo = (b < 64) ? Alo : Blo;
    int i = (b & 63) * 256 + threadIdx.x;     // 64 blocks * 256 = 16384
    int k = i >> 7, n = i & 127;
    float w = W[i];
    unsigned short hi = f2b(w);
    unsigned short lo = f2b(w - b2f(hi));
    Hi[n * D + k] = hi;
    Lo[n * D + k] = lo;
}

// ---------------------------------------------------------------------------
// Bucket edges by src and nodes by graph id. One returning int atomic per
// element; counters padded to spread fabric-atomic line serialization
// (dense cnt = 16 counters/line = ~256 serialized atomics/line was the
// round-4 bottleneck theory; CPN=4 gives 4x spread while staying L2-sized).
__global__ __launch_bounds__(256) void k_build(
        const int* __restrict__ esrc, const int* __restrict__ edst,
        const float* __restrict__ eval,
        int* __restrict__ cnt, int2* __restrict__ edata, int E,
        const int* __restrict__ bids, const float* __restrict__ bval,
        int* __restrict__ gcnt, int2* __restrict__ gdata, int N) {
    int i = blockIdx.x * 256 + threadIdx.x;
    if (i < E) {
        int s = esrc[i];
        int slot = atomicAdd(&cnt[s * CPN], 1);
        if (slot < CAP) {
            int2 d; d.x = edst[i]; d.y = __float_as_int(eval[i]);
            edata[(size_t)s * CAP + slot] = d;
        }
    }
    if (i < N) {
        int g = bids[i];
        int slot = atomicAdd(&gcnt[g * CPG], 1);
        if (slot < GCAP) {
            int2 d; d.x = i; d.y = __float_as_int(bval[i]);
            gdata[(size_t)g * GCAP + slot] = d;
        }
    }
}

// ---------------------------------------------------------------------------
// Fused: hw = (relu(x @ W_in + b_in)) @ W_gcn, output packed bf16.
// GEMM1 fp32-accurate via hi/lo bf16 split (3 MFMAs/tile); h parked bf16 in
// wave-private LDS (C-layout -> A-layout), GEMM2 = 2 MFMAs vs split W2.
__global__ __launch_bounds__(256) void k_gemm_fused(
        const float* __restrict__ X,
        const unsigned short* __restrict__ W1hi, const unsigned short* __restrict__ W1lo,
        const float* __restrict__ bias1,
        const unsigned short* __restrict__ W2hi, const unsigned short* __restrict__ W2lo,
        unsigned short* __restrict__ HW, int N) {
    __shared__ unsigned short lds[4 * 16 * LSTRIDE];      // 16.9 KB
    const int wave = threadIdx.x >> 6;
    const int lane = threadIdx.x & 63;
    const int q = lane >> 4;
    const int l15 = lane & 15;
    const int row0 = blockIdx.x * 64 + wave * 16;
    unsigned short* tile = lds + wave * 16 * LSTRIDE;

    int arow = row0 + l15;
    if (arow >= N) arow = N - 1;                          // clamp; stores guarded
    const float* xrow = X + (size_t)arow * D;

    f32x4 acc[8];
#pragma unroll
    for (int t = 0; t < 8; t++) acc[t] = (f32x4){0.f, 0.f, 0.f, 0.f};

    // ---- GEMM 1: acc = x @ W_in ----
#pragma unroll
    for (int kk = 0; kk < 4; kk++) {
        float4 f0 = *(const float4*)(xrow + kk * 32 + q * 8);
        float4 f1 = *(const float4*)(xrow + kk * 32 + q * 8 + 4);
        float fv[8] = {f0.x, f0.y, f0.z, f0.w, f1.x, f1.y, f1.z, f1.w};
        short8 ahi, alo;
#pragma unroll
        for (int j = 0; j < 8; j++) {
            unsigned short h = f2b(fv[j]);
            ahi[j] = (short)h;
            alo[j] = (short)f2b(fv[j] - b2f(h));
        }
#pragma unroll
        for (int t = 0; t < 8; t++) {
            size_t woff = (size_t)(t * 16 + l15) * D + kk * 32 + q * 8;
            short8 bhi = *(const short8*)(W1hi + woff);
            short8 blo = *(const short8*)(W1lo + woff);
            acc[t] = __builtin_amdgcn_mfma_f32_16x16x32_bf16(ahi, bhi, acc[t], 0, 0, 0);
            acc[t] = __builtin_amdgcn_mfma_f32_16x16x32_bf16(ahi, blo, acc[t], 0, 0, 0);
            acc[t] = __builtin_amdgcn_mfma_f32_16x16x32_bf16(alo, bhi, acc[t], 0, 0, 0);
        }
    }

    // ---- bias + relu, park h (bf16) in wave-private LDS ----
#pragma unroll
    for (int t = 0; t < 8; t++) {
        int col = t * 16 + l15;
        float bv = bias1[col];
#pragma unroll
        for (int r = 0; r < 4; r++) {
            float v = acc[t][r] + bv;
            v = v > 0.f ? v : 0.f;
            tile[(q * 4 + r) * LSTRIDE + col] = f2b(v);
        }
    }

    // ---- GEMM 2: acc = h @ W_gcn ----
#pragma unroll
    for (int t = 0; t < 8; t++) acc[t] = (f32x4){0.f, 0.f, 0.f, 0.f};
#pragma unroll
    for (int kk = 0; kk < 4; kk++) {
        short8 ahi = *(const short8*)(tile + l15 * LSTRIDE + kk * 32 + q * 8);
#pragma unroll
        for (int t = 0; t < 8; t++) {
            size_t woff = (size_t)(t * 16 + l15) * D + kk * 32 + q * 8;
            short8 bhi = *(const short8*)(W2hi + woff);
            short8 blo = *(const short8*)(W2lo + woff);
            acc[t] = __builtin_amdgcn_mfma_f32_16x16x32_bf16(ahi, bhi, acc[t], 0, 0, 0);
            acc[t] = __builtin_amdgcn_mfma_f32_16x16x32_bf16(ahi, blo, acc[t], 0, 0, 0);
        }
    }

    // ---- store hw as bf16 ----
#pragma unroll
    for (int t = 0; t < 8; t++) {
        int col = t * 16 + l15;
#pragma unroll
        for (int r = 0; r < 4; r++) {
            int row = row0 + q * 4 + r;
            if (row < N) HW[(size_t)row * D + col] = f2b(acc[t][r]);
        }
    }
}

// ---------------------------------------------------------------------------
// One wave per node: gather its edges' bf16 hw rows (1 uint/lane/edge),
// register-accumulate fp32, relu, l2-normalize, write h_struct. No atomics.
__global__ __launch_bounds__(256) void k_agg_finalize(
        const int* __restrict__ cnt, const int2* __restrict__ edata,
        const unsigned int* __restrict__ hw32,   // hw as packed 2xbf16
        float* __restrict__ hstruct, int N) {
    const int lane = threadIdx.x & 63;
    const int node = blockIdx.x * 4 + (threadIdx.x >> 6);
    if (node >= N) return;
    int deg = cnt[node * CPN];
    if (deg > CAP) deg = CAP;

    int myDst = 0; float myVal = 0.f;
    if (lane < deg) {
        int2 ed = edata[(size_t)node * CAP + lane];
        myDst = ed.x; myVal = __int_as_float(ed.y);
    }

    float a0 = 0.f, a1 = 0.f;
#pragma unroll 4
    for (int j = 0; j < deg; j++) {
        int dj = __shfl(myDst, j, 64);
        float vj = __shfl(myVal, j, 64);
        unsigned int p = hw32[(size_t)dj * 64 + lane];
        a0 = fmaf(vj, b2f((unsigned short)(p & 0xffffu)), a0);
        a1 = fmaf(vj, b2f((unsigned short)(p >> 16)), a1);
    }

    a0 = a0 > 0.f ? a0 : 0.f;
    a1 = a1 > 0.f ? a1 : 0.f;
    float ss = a0 * a0 + a1 * a1;
#pragma unroll
    for (int m = 1; m < 64; m <<= 1) ss += __shfl_xor(ss, m, 64);
    float scale = 1.0f / fmaxf(sqrtf(ss), 1e-12f);
    float2 o; o.x = a0 * scale; o.y = a1 * scale;
    *(float2*)(hstruct + (size_t)node * D + 2 * lane) = o;
}

// ---------------------------------------------------------------------------
// One wave per graph: weighted-gather h_struct rows, then
// l2norm(relu(hg @ W_g + b_g)) via shfl-broadcast dot.
__global__ __launch_bounds__(256) void k_graph_finalize(
        const int* __restrict__ gcnt, const int2* __restrict__ gdata,
        const float* __restrict__ hstruct,
        const float* __restrict__ Wg, const float* __restrict__ bg,
        float* __restrict__ out, int G) {
    const int lane = threadIdx.x & 63;
    const int g = blockIdx.x * 4 + (threadIdx.x >> 6);
    if (g >= G) return;
    int deg = gcnt[g * CPG];
    if (deg > GCAP) deg = GCAP;
    const int c0 = 2 * lane;

    float a0 = 0.f, a1 = 0.f;   // hg[g][c0], hg[g][c0+1]
    for (int base = 0; base < deg; base += 64) {
        int nrem = deg - base; if (nrem > 64) nrem = 64;
        int myNode = 0; float myW = 0.f;
        if (lane < nrem) {
            int2 ed = gdata[(size_t)g * GCAP + base + lane];
            myNode = ed.x; myW = __int_as_float(ed.y);
        }
#pragma unroll 4
        for (int j = 0; j < nrem; j++) {
            int nj = __shfl(myNode, j, 64);
            float wj = __shfl(myW, j, 64);
            float2 hs = *(const float2*)(hstruct + (size_t)nj * D + c0);
            a0 = fmaf(wj, hs.x, a0);
            a1 = fmaf(wj, hs.y, a1);
        }
    }

    float o0 = 0.f, o1 = 0.f;
#pragma unroll 2
    for (int k = 0; k < D; k++) {
        float xv = (k & 1) ? __shfl(a1, k >> 1, 64) : __shfl(a0, k >> 1, 64);
        float2 w = *(const float2*)(Wg + (size_t)k * D + c0);
        o0 = fmaf(xv, w.x, o0);
        o1 = fmaf(xv, w.y, o1);
    }
    o0 += bg[c0];
    o1 += bg[c0 + 1];
    o0 = o0 > 0.f ? o0 : 0.f;
    o1 = o1 > 0.f ? o1 : 0.f;
    float ss = o0 * o0 + o1 * o1;
#pragma unroll
    for (int m = 1; m < 64; m <<= 1) ss += __shfl_xor(ss, m, 64);
    float scale = 1.0f / fmaxf(sqrtf(ss), 1e-12f);
    float2 o; o.x = o0 * scale; o.y = o1 * scale;
    *(float2*)(out + (size_t)g * D + c0) = o;
}

// ---------------------------------------------------------------------------
extern "C" void kernel_launch(void* const* d_in, const int* in_sizes, int n_in,
                              void* d_out, int out_size, void* d_ws, size_t ws_size,
                              hipStream_t stream) {
    const float* x     = (const float*)d_in[0];
    const int*   esrc  = (const int*)d_in[1];
    const int*   edst  = (const int*)d_in[2];
    const float* eval  = (const float*)d_in[3];
    const int*   bids  = (const int*)d_in[4];
    const float* bval  = (const float*)d_in[5];
    const float* W_in  = (const float*)d_in[6];
    const float* b_in  = (const float*)d_in[7];
    const float* W_gcn = (const float*)d_in[8];
    const float* W_g   = (const float*)d_in[9];
    const float* b_g   = (const float*)d_in[10];

    const int N = in_sizes[4];      // batch_ids length = num nodes
    const int E = in_sizes[1];      // edge_src length
    const int G = 1024;             // num_graphs (problem constant)

    char* ws = (char*)d_ws;
    unsigned short* whi_in  = (unsigned short*)ws; ws += (size_t)D * D * 2;
    unsigned short* wlo_in  = (unsigned short*)ws; ws += (size_t)D * D * 2;
    unsigned short* whi_gcn = (unsigned short*)ws; ws += (size_t)D * D * 2;
    unsigned short* wlo_gcn = (unsigned short*)ws; ws += (size_t)D * D * 2;
    int*   cnt   = (int*)ws;   ws += (size_t)N * CPN * 4;    // 1.6 MB padded
    int*   gcnt  = (int*)ws;   ws += (size_t)G * CPG * 4;    // 64 KB padded
    unsigned short* hw = (unsigned short*)ws; ws += (size_t)N * D * 2;  // hw, bf16
    int2*  edata = (int2*)ws;  ws += (size_t)N * CAP * 8;    // {dst, val} per src
    int2*  gdata = (int2*)ws;  ws += (size_t)G * GCAP * 8;   // {node, bval} per graph

    // weights prep + counter zeroing in one dispatch
    const int zmax = (N > G ? N : G);
    const int zblocks = (zmax + 255) / 256;
    k_prep<<<128 + zblocks, 256, 0, stream>>>(W_in, whi_in, wlo_in,
                                              W_gcn, whi_gcn, wlo_gcn,
                                              cnt, N, gcnt, G);

    int mb = ((E > N ? E : N) + 255) / 256;
    k_build<<<mb, 256, 0, stream>>>(esrc, edst, eval, cnt, edata, E,
                                    bids, bval, gcnt, gdata, N);

    const int gb = (N + 63) / 64;
    k_gemm_fused<<<gb, 256, 0, stream>>>(x, whi_in, wlo_in, b_in,
                                         whi_gcn, wlo_gcn, hw, N);

    float* hstruct = (float*)d_out;
    float* hgraph  = hstruct + (size_t)N * D;

    k_agg_finalize<<<(N + 3) / 4, 256, 0, stream>>>(cnt, edata,
                                                    (const unsigned int*)hw, hstruct, N);
    k_graph_finalize<<<(G + 3) / 4, 256, 0, stream>>>(gcnt, gdata, hstruct, W_g, b_g, hgraph, G);
}